// Round 4
// baseline (554.749 us; speedup 1.0000x reference)
//
#include <hip/hip_runtime.h>
#include <hip/hip_bf16.h>

typedef unsigned short u16;
typedef short bf16x8 __attribute__((ext_vector_type(8)));
typedef float f32x4 __attribute__((ext_vector_type(4)));
typedef unsigned short u16x8 __attribute__((ext_vector_type(8)));

#define GLL16(gp, lp) __builtin_amdgcn_global_load_lds( \
    (__attribute__((address_space(1))) const unsigned int*)(gp), \
    (__attribute__((address_space(3))) unsigned int*)(lp), 16, 0, 0)

// HW RNE f32->bf16 (compiler pairs these into v_cvt_pk_bf16_f32)
static __device__ __forceinline__ u16 f2bf(float f){
  return __builtin_bit_cast(u16, __float2bfloat16(f));
}

// ---------------- transpose + convert: dst[b][c][r] = bf16(src[b][r][c]), r zero-padded to Rpad
__global__ void transpose_f32(const float* __restrict__ src, u16* __restrict__ dst,
                              int R, int C, int Rpad, long sB, long dB){
  __shared__ u16 tile[32][33];
  const int b = blockIdx.z;
  src += (long)b*sB; dst += (long)b*dB;
  const int r0 = blockIdx.x*32, c0 = blockIdx.y*32;
  const int j = threadIdx.x & 31, i0 = threadIdx.x >> 5;
  #pragma unroll
  for (int ii=0; ii<32; ii+=8){
    int r = r0+i0+ii, c = c0+j;
    u16 v = 0;
    if (r < R && c < C) v = f2bf(src[(long)r*C + c]);
    tile[i0+ii][j] = v;
  }
  __syncthreads();
  #pragma unroll
  for (int ii=0; ii<32; ii+=8){
    int c = c0+i0+ii, r = r0+j;
    if (c < C && r < Rpad) dst[(long)c*Rpad + r] = tile[j][i0+ii];
  }
}

// ---------------- G1: edges[b,e,d] = sum_n H[b,e,n]*ori[b,n,d]  M=8000 N=256 K=2048pad
// 64x256 tile, 256 thr / 4 waves (1M x 4N of 64x64). Grid 500 -> ~2 blocks/CU resident.
// Also emits HT[b][n][e] = bf16(H[b][e][n]). 8000 = 125*64: no M guards.
__global__ __launch_bounds__(256,2) void g1_kernel(
    const float* __restrict__ Hm, const u16* __restrict__ oriT,
    u16* __restrict__ edges, u16* __restrict__ HT){
  __shared__ u16 As[2][64*32];
  __shared__ u16 Bs[2][256*32];
  __shared__ u16 At[2][32*72];       // k-major copy for transposed HT write; row XOR-swizzled
  const int b = blockIdx.y, bm = blockIdx.x*64;
  const int tid = threadIdx.x;
  const int w = tid>>6, quad = (tid&63)>>4, l16 = tid&15;
  const int wn = w*64;
  const float* Ab = Hm + (size_t)b*8000*2000 + (size_t)bm*2000;
  const u16*  Bb = oriT + (size_t)b*256*2048;
  u16* HTb = HT + (size_t)b*2048*8000;

  float4 pa[2];
  auto loadA = [&](int kt, bool guard){
    const int k0 = kt*32;
    #pragma unroll
    for (int i=0;i<2;i++){
      int idx = i*256+tid, row = idx>>3, c4 = (idx&7)*4;
      if (!guard){
        pa[i] = *(const float4*)(Ab + (size_t)row*2000 + k0+c4);
      } else {
        bool ok = (k0+c4 < 2000);
        pa[i] = ok ? *(const float4*)(Ab + (size_t)row*2000 + k0+c4) : make_float4(0.f,0.f,0.f,0.f);
      }
    }
  };
  auto storeA = [&](int kt){
    const int buf = kt&1;
    #pragma unroll
    for (int i=0;i<2;i++){
      int idx = i*256+tid, row = idx>>3, c4 = (idx&7)*4;
      ushort4 o; o.x=f2bf(pa[i].x); o.y=f2bf(pa[i].y); o.z=f2bf(pa[i].z); o.w=f2bf(pa[i].w);
      *(ushort4*)(&As[buf][idx*4]) = o;
      At[buf][(c4+0)*72 + (row ^ ((((c4+0)>>3)&3)<<3))] = o.x;
      At[buf][(c4+1)*72 + (row ^ ((((c4+1)>>3)&3)<<3))] = o.y;
      At[buf][(c4+2)*72 + (row ^ ((((c4+2)>>3)&3)<<3))] = o.z;
      At[buf][(c4+3)*72 + (row ^ ((((c4+3)>>3)&3)<<3))] = o.w;
    }
  };
  auto stageB = [&](int kt){
    const int buf = kt&1, k0 = kt*32;
    #pragma unroll
    for (int i=0;i<4;i++){
      int idx = i*256+tid;
      int row = idx>>2, c8 = (idx&3)*8;
      GLL16(Bb + (size_t)row*2048 + k0+c8, &Bs[buf][(i*256 + w*64)*8]);
    }
  };

  f32x4 acc[4][4];
  #pragma unroll
  for (int i=0;i<4;i++)
    #pragma unroll
    for (int j=0;j<4;j++) acc[i][j] = (f32x4){0.f,0.f,0.f,0.f};

  loadA(0, false); stageB(0);
  for (int kt=0; kt<64; kt++){
    storeA(kt);
    __syncthreads();
    if (kt+1 < 64){ loadA(kt+1, kt+1 >= 62); stageB(kt+1); }
    const int buf = kt&1, k0 = kt*32;
    // HT write: 32(k) x 64(m) tile, coalesced 16B stores
    {
      int kk = tid>>3, m0 = (tid&7)*8;
      u16x8 v = *(const u16x8*)(&At[buf][kk*72 + (m0 ^ (((kk>>3)&3)<<3))]);
      *(u16x8*)(HTb + (size_t)(k0+kk)*8000 + bm + m0) = v;
    }
    bf16x8 af[4], bf[4];
    #pragma unroll
    for (int mi=0;mi<4;mi++) af[mi] = *(const bf16x8*)(&As[buf][(mi*16+l16)*32 + quad*8]);
    #pragma unroll
    for (int ni=0;ni<4;ni++) bf[ni] = *(const bf16x8*)(&Bs[buf][(wn+ni*16+l16)*32 + quad*8]);
    #pragma unroll
    for (int mi=0;mi<4;mi++)
      #pragma unroll
      for (int ni=0;ni<4;ni++)
        acc[mi][ni] = __builtin_amdgcn_mfma_f32_16x16x32_bf16(af[mi], bf[ni], acc[mi][ni], 0,0,0);
  }
  #pragma unroll
  for (int mi=0;mi<4;mi++){
    #pragma unroll
    for (int r=0;r<4;r++){
      int gm = bm + mi*16 + quad*4 + r;
      u16* dst = edges + ((size_t)b*8000 + gm)*256;
      #pragma unroll
      for (int ni=0;ni<4;ni++) dst[wn + ni*16 + l16] = f2bf(acc[mi][ni][r]);
    }
  }
}

// ---------------- MLP fused (m1+m2+transpose): 64 edge-rows per block, all 5 types.
// 256 thr / 4 waves. LDS ~66KB -> 2 blocks/CU. Edges tile re-staged per t (L2-resident).
// GEMM2 transposed (rows=d, cols=m) so epilogue writes EFt directly.
__global__ __launch_bounds__(256,2) void mlp_kernel(
    const u16* __restrict__ edges, const u16* __restrict__ W1T, const u16* __restrict__ W2T,
    const float* __restrict__ b1, const float* __restrict__ b2,
    const float* __restrict__ edist, u16* __restrict__ EFt){
  __shared__ u16 As[2][64*32];    // edges k-slice staging
  __shared__ u16 Hs[4*2048];      // hidden tile [kk][64 m][32 h]
  __shared__ u16 Bs[2][256*32];   // W staging (GEMM1 uses 128 rows, GEMM2 256)
  __shared__ float eds[320], b1s[640], b2s[1280];
  const int bm = blockIdx.x*64;
  const int tid = threadIdx.x;
  const int w = tid>>6, quad = (tid&63)>>4, l16 = tid&15;
  const int wh1 = w*32;            // GEMM1: 64m x 128h, 1M x 4H waves
  const int wd2 = w*64;            // GEMM2: 256d x 64m, 4D x 1M waves

  for (int i=tid;i<320;i+=256) eds[i] = edist[(size_t)bm*5 + i];
  for (int i=tid;i<640;i+=256) b1s[i] = b1[i];
  for (int i=tid;i<1280;i+=256) b2s[i] = b2[i];

  const u16* Eb = edges + (size_t)bm*256;

  auto stageA = [&](int kt){           // edges tile [64 m][32 k], 4KB
    const int buf = kt&1;
    int row = tid>>2, c8 = (tid&3)*8;
    GLL16(Eb + (size_t)row*256 + kt*32 + c8, &As[buf][(w*64)*8]);
  };
  auto stageW1 = [&](int t, int kt){   // W1T[t] tile [128 h][32 k], 8KB
    const int buf = kt&1;
    #pragma unroll
    for (int i=0;i<2;i++){
      int idx = i*256+tid, row = idx>>2, c8 = (idx&3)*8;
      GLL16(W1T + ((size_t)t*128 + row)*256 + kt*32 + c8, &Bs[buf][(i*256 + w*64)*8]);
    }
  };
  auto stageW2 = [&](int t, int kk){   // W2T[t] tile [256 d][32 k], 16KB
    const int buf = kk&1;
    #pragma unroll
    for (int i=0;i<4;i++){
      int idx = i*256+tid, row = idx>>2, c8 = (idx&3)*8;
      GLL16(W2T + ((size_t)t*256 + row)*128 + kk*32 + c8, &Bs[buf][(i*256 + w*64)*8]);
    }
  };

  f32x4 acc2[4][4];
  #pragma unroll
  for (int i=0;i<4;i++)
    #pragma unroll
    for (int j=0;j<4;j++) acc2[i][j] = (f32x4){0.f,0.f,0.f,0.f};

  stageA(0); stageW1(0,0);
  for (int t=0;t<5;t++){
    f32x4 acc1[4][2];
    #pragma unroll
    for (int i=0;i<4;i++){ acc1[i][0] = (f32x4){0.f,0.f,0.f,0.f}; acc1[i][1] = (f32x4){0.f,0.f,0.f,0.f}; }
    // ---- GEMM1: hidden = edges @ W1T[t]
    for (int kt=0;kt<8;kt++){
      __syncthreads();
      if (kt<7){ stageA(kt+1); stageW1(t,kt+1); } else stageW2(t,0);
      const int buf = kt&1;
      bf16x8 af[4], bfr[2];
      #pragma unroll
      for (int mi=0;mi<4;mi++) af[mi] = *(const bf16x8*)(&As[buf][(mi*16+l16)*32 + quad*8]);
      #pragma unroll
      for (int ni=0;ni<2;ni++) bfr[ni] = *(const bf16x8*)(&Bs[buf][(wh1+ni*16+l16)*32 + quad*8]);
      #pragma unroll
      for (int mi=0;mi<4;mi++)
        #pragma unroll
        for (int ni=0;ni<2;ni++)
          acc1[mi][ni] = __builtin_amdgcn_mfma_f32_16x16x32_bf16(af[mi], bfr[ni], acc1[mi][ni], 0,0,0);
    }
    __syncthreads();
    // ---- epilogue1: relu + bias + ed-scale -> Hs (bf16)
    #pragma unroll
    for (int mi=0;mi<4;mi++){
      #pragma unroll
      for (int r=0;r<4;r++){
        int lrow = mi*16 + quad*4 + r;
        float s = eds[lrow*5 + t];
        #pragma unroll
        for (int ni=0;ni<2;ni++){
          int ch = wh1 + ni*16 + l16;
          float v = fmaxf(acc1[mi][ni][r] + b1s[t*128 + ch], 0.f) * s;
          Hs[(ch>>5)*2048 + lrow*32 + (ch&31)] = f2bf(v);
        }
      }
    }
    // ---- GEMM2 (transposed): acc2[d][m] += W2T[t] x hidden
    for (int kk=0;kk<4;kk++){
      __syncthreads();
      if (kk<3) stageW2(t,kk+1);
      else if (t<4){ stageA(0); stageW1(t+1,0); }
      const int buf = kk&1;
      bf16x8 af2[4], bf2[4];
      #pragma unroll
      for (int mi=0;mi<4;mi++) af2[mi] = *(const bf16x8*)(&Bs[buf][(wd2+mi*16+l16)*32 + quad*8]);
      #pragma unroll
      for (int ni=0;ni<4;ni++) bf2[ni] = *(const bf16x8*)(&Hs[kk*2048 + (ni*16+l16)*32 + quad*8]);
      #pragma unroll
      for (int mi=0;mi<4;mi++)
        #pragma unroll
        for (int ni=0;ni<4;ni++)
          acc2[mi][ni] = __builtin_amdgcn_mfma_f32_16x16x32_bf16(af2[mi], bf2[ni], acc2[mi][ni], 0,0,0);
    }
  }
  // ---- epilogue2: add bias-dot, write EFt[b][d][e] directly (rows=d, cols=e)
  #pragma unroll
  for (int mi=0;mi<4;mi++){
    #pragma unroll
    for (int r=0;r<4;r++){
      int d = wd2 + mi*16 + quad*4 + r;
      #pragma unroll
      for (int ni=0;ni<4;ni++){
        int mc = ni*16 + l16;
        float bias = eds[mc*5+0]*b2s[d] + eds[mc*5+1]*b2s[256+d] + eds[mc*5+2]*b2s[512+d]
                   + eds[mc*5+3]*b2s[768+d] + eds[mc*5+4]*b2s[1024+d];
        int e = bm + mc;
        int bq = e / 8000;
        EFt[((size_t)bq*256 + d)*8000 + (e - bq*8000)] = f2bf(acc2[mi][ni][r] + bias);
      }
    }
  }
}

// ---------------- G3: part[ks][b,m,d] = sum_{e in slice} HT[b,m,e]*EFt[b,d,e]
// 64x256 tile, 256 thr / 4 waves, grid 512 (32 m x 4 ks x 4 b) -> 2 blocks/CU.
// XCD-chunked swizzle keeps one b per XCD pair (EFt[b]=4MB fits L2).
__global__ __launch_bounds__(256,2) void g3_kernel(
    const u16* __restrict__ HT, const u16* __restrict__ EFt, float* __restrict__ part){
  __shared__ u16 As[2][64*32];
  __shared__ u16 Bs[2][256*32];
  const int wg = ((int)blockIdx.x & 7)*64 + ((int)blockIdx.x >> 3);   // bijective, 512%8==0
  const int bm = (wg & 31)*64, ks = (wg>>5)&3, b = wg>>7;
  const int tid = threadIdx.x;
  const int w = tid>>6, quad = (tid&63)>>4, l16 = tid&15;
  const int wn = w*64;
  const u16* Ab = HT + (size_t)b*2048*8000 + (size_t)bm*8000;
  const u16* Bb = EFt + (size_t)b*256*8000;
  const int it0 = (250*ks)/4, it1 = (250*(ks+1))/4;

  auto stage = [&](int kt){
    const int buf = kt&1, k0 = kt*32;
    {
      int row = tid>>2, c8 = (tid&3)*8;
      GLL16(Ab + (size_t)row*8000 + k0+c8, &As[buf][(w*64)*8]);
    }
    #pragma unroll
    for (int i=0;i<4;i++){
      int idx = i*256+tid, row = idx>>2, c8 = (idx&3)*8;
      GLL16(Bb + (size_t)row*8000 + k0+c8, &Bs[buf][(i*256 + w*64)*8]);
    }
  };

  f32x4 acc[4][4];
  #pragma unroll
  for (int i=0;i<4;i++)
    #pragma unroll
    for (int j=0;j<4;j++) acc[i][j] = (f32x4){0.f,0.f,0.f,0.f};

  stage(it0);
  for (int kt=it0; kt<it1; kt++){
    __syncthreads();
    if (kt+1 < it1) stage(kt+1);
    const int buf = kt&1;
    bf16x8 af[4], bf[4];
    #pragma unroll
    for (int mi=0;mi<4;mi++) af[mi] = *(const bf16x8*)(&As[buf][(mi*16+l16)*32 + quad*8]);
    #pragma unroll
    for (int ni=0;ni<4;ni++) bf[ni] = *(const bf16x8*)(&Bs[buf][(wn+ni*16+l16)*32 + quad*8]);
    #pragma unroll
    for (int mi=0;mi<4;mi++)
      #pragma unroll
      for (int ni=0;ni<4;ni++)
        acc[mi][ni] = __builtin_amdgcn_mfma_f32_16x16x32_bf16(af[mi], bf[ni], acc[mi][ni], 0,0,0);
  }
  float* dst0 = part + ((size_t)(b*4 + ks)*2048)*256;
  #pragma unroll
  for (int mi=0;mi<4;mi++){
    #pragma unroll
    for (int r=0;r<4;r++){
      int gm = bm + mi*16 + quad*4 + r;
      float* dst = dst0 + (size_t)gm*256;
      #pragma unroll
      for (int ni=0;ni<4;ni++) dst[wn + ni*16 + l16] = acc[mi][ni][r];
    }
  }
}

// ---------------- assemble: out[b,n,:256] = sum_ks part ; out[b,n,256:] = ori[b,n,:]
__global__ void assemble_kernel(const float* __restrict__ part, const float* __restrict__ ori,
                                float* __restrict__ out){
  const int b = blockIdx.y;
  int u = blockIdx.x*256 + threadIdx.x;          // 500*256 = 128000 = 2000*64
  int n = u>>6, c4 = (u&63)*4;
  f32x4 s = (f32x4){0.f,0.f,0.f,0.f};
  #pragma unroll
  for (int ks=0; ks<4; ks++)
    s += *(const f32x4*)(part + ((size_t)(b*4+ks)*2048 + n)*256 + c4);
  float* dst = out + ((size_t)(b*2000+n))*512;
  *(f32x4*)(dst + c4) = s;
  *(f32x4*)(dst + 256 + c4) = *(const f32x4*)(ori + ((size_t)(b*2000+n))*256 + c4);
}

extern "C" void kernel_launch(void* const* d_in, const int* in_sizes, int n_in,
                              void* d_out, int out_size, void* d_ws, size_t ws_size,
                              hipStream_t stream) {
  const float* ed  = (const float*)d_in[0];   // [4,8000,5]
  const float* Hm  = (const float*)d_in[1];   // [4,8000,2000]
  const float* ori = (const float*)d_in[2];   // [4,2000,256]
  const float* W1  = (const float*)d_in[3];   // [5,256,128]
  const float* b1  = (const float*)d_in[4];   // [5,128]
  const float* W2  = (const float*)d_in[5];   // [5,128,256]
  const float* b2  = (const float*)d_in[6];   // [5,256]
  float* out = (float*)d_out;                 // [4,2000,512]
  char* ws = (char*)d_ws;

  u16* HT    = (u16*)(ws);                 // 4*2048*8000*2 = 131,072,000
  u16* oriT  = (u16*)(ws + 131072000);     // 4*256*2048*2  =   4,194,304
  u16* W1T   = (u16*)(ws + 135266304);     // 5*128*256*2   =     327,680
  u16* W2T   = (u16*)(ws + 135593984);     // 5*256*128*2   =     327,680
  u16* edges = (u16*)(ws + 135921664);     // 32000*256*2   =  16,384,000
  u16* EFt   = (u16*)(ws + 152305664);     // 4*256*8000*2  =  16,384,000
  float* part = (float*)(ws + 168689664);  // 4*4*2048*256*4 = 33,554,432 (end ~202.2 MB)

  hipLaunchKernelGGL(transpose_f32, dim3(64,8,4), dim3(256), 0, stream,
                     ori, oriT, 2000, 256, 2048, 512000L, 524288L);
  hipLaunchKernelGGL(transpose_f32, dim3(8,4,5), dim3(256), 0, stream,
                     W1, W1T, 256, 128, 256, 32768L, 32768L);
  hipLaunchKernelGGL(transpose_f32, dim3(4,8,5), dim3(256), 0, stream,
                     W2, W2T, 128, 256, 128, 32768L, 32768L);

  hipLaunchKernelGGL(g1_kernel, dim3(125,4), dim3(256), 0, stream, Hm, oriT, edges, HT);
  hipLaunchKernelGGL(mlp_kernel, dim3(500), dim3(256), 0, stream,
                     edges, W1T, W2T, b1, b2, ed, EFt);
  hipLaunchKernelGGL(g3_kernel, dim3(512), dim3(256), 0, stream, HT, EFt, part);
  hipLaunchKernelGGL(assemble_kernel, dim3(500,4), dim3(256), 0, stream, part, ori, out);

  (void)in_sizes; (void)n_in; (void)ws_size;
}

// Round 5
// 529.205 us; speedup vs baseline: 1.0483x; 1.0483x over previous
//
#include <hip/hip_runtime.h>
#include <hip/hip_bf16.h>

typedef unsigned short u16;
typedef short bf16x8 __attribute__((ext_vector_type(8)));
typedef float f32x4 __attribute__((ext_vector_type(4)));
typedef unsigned short u16x8 __attribute__((ext_vector_type(8)));

#define GLL16(gp, lp) __builtin_amdgcn_global_load_lds( \
    (__attribute__((address_space(1))) const unsigned int*)(gp), \
    (__attribute__((address_space(3))) unsigned int*)(lp), 16, 0, 0)

// HW RNE f32->bf16 (compiler pairs these into v_cvt_pk_bf16_f32)
static __device__ __forceinline__ u16 f2bf(float f){
  return __builtin_bit_cast(u16, __float2bfloat16(f));
}

// ---------------- transpose + convert: dst[b][c][r] = bf16(src[b][r][c]), r zero-padded to Rpad
__global__ void transpose_f32(const float* __restrict__ src, u16* __restrict__ dst,
                              int R, int C, int Rpad, long sB, long dB){
  __shared__ u16 tile[32][33];
  const int b = blockIdx.z;
  src += (long)b*sB; dst += (long)b*dB;
  const int r0 = blockIdx.x*32, c0 = blockIdx.y*32;
  const int j = threadIdx.x & 31, i0 = threadIdx.x >> 5;
  #pragma unroll
  for (int ii=0; ii<32; ii+=8){
    int r = r0+i0+ii, c = c0+j;
    u16 v = 0;
    if (r < R && c < C) v = f2bf(src[(long)r*C + c]);
    tile[i0+ii][j] = v;
  }
  __syncthreads();
  #pragma unroll
  for (int ii=0; ii<32; ii+=8){
    int c = c0+i0+ii, r = r0+j;
    if (c < C && r < Rpad) dst[(long)c*Rpad + r] = tile[j][i0+ii];
  }
}

// ---------------- G1+MLP fused: per block, 128 edge rows of one batch.
// Phase 1 (= R2 g1): edges_tile[128x256] = H_tile @ ori  (acc in regs), emits HT.
// Phase 2 (= R2 mlp on the in-LDS tile): per type t, GEMM1+relu+ed-scale -> Hs,
// GEMM2 transposed (rows=d, cols=m) accumulating acc2; epilogue writes EFt directly.
// LDS 141312 B (1 block/CU): Bs 32K | eds/b1s/b2s 10K | union{As+At 33K , Es 64K}+Hs 32K.
__global__ __launch_bounds__(512,2) void g1mlp_kernel(
    const float* __restrict__ Hm, const u16* __restrict__ oriT,
    const u16* __restrict__ W1T, const u16* __restrict__ W2T,
    const float* __restrict__ b1, const float* __restrict__ b2,
    const float* __restrict__ edist, u16* __restrict__ HT, u16* __restrict__ EFt){
  __shared__ __align__(16) char smem[141312];
  u16*   Bs  = (u16*)(smem);              // [2][8192]  32768 B (B/W staging)
  float* eds = (float*)(smem + 32768);    // 640 f      2560 B
  float* b1s = (float*)(smem + 35328);    // 640 f      2560 B
  float* b2s = (float*)(smem + 37888);    // 1280 f     5120 B
  u16*   As  = (u16*)(smem + 43008);      // [2][4096]  16384 B  (phase 1)
  u16*   At  = (u16*)(smem + 59392);      // [2][4352]  17408 B  (phase 1)
  u16*   Es  = (u16*)(smem + 43008);      // [8][4096]  65536 B  (phase 2, aliases As+At)
  u16*   Hs  = (u16*)(smem + 108544);     // [4][4096]  32768 B  (phase 2)

  const int b = blockIdx.y, bm = blockIdx.x*128;
  const int tid = threadIdx.x;
  const int w = tid>>6, quad = (tid&63)>>4, l16 = tid&15;
  const int wm = (w&1)*64, wn = (w>>1)*64;      // phase1: 2M x 4N waves, 64x64 each
  const float* Ab = Hm + (size_t)b*8000*2000 + (size_t)bm*2000;
  const u16*  Bb = oriT + (size_t)b*256*2048;
  u16* HTb = HT + (size_t)b*2048*8000;
  const bool edge_blk = (bm == 7936);           // last M-block: rows 64..127 OOB

  // small tables (visible after first barrier; never rewritten)
  for (int i=tid;i<640;i+=512){
    int e = bm + i/5;
    eds[i] = (e < 8000) ? edist[((size_t)b*8000 + bm)*5 + i] : 0.f;
  }
  for (int i=tid;i<640;i+=512)  b1s[i] = b1[i];
  for (int i=tid;i<1280;i+=512) b2s[i] = b2[i];

  float4 pa[2];
  auto loadA = [&](int kt, bool guard){
    const int k0 = kt*32;
    #pragma unroll
    for (int i=0;i<2;i++){
      int idx = i*512+tid, row = idx>>3, c4 = (idx&7)*4;
      if (!guard){
        pa[i] = *(const float4*)(Ab + (size_t)row*2000 + k0+c4);
      } else {
        bool ok = (bm+row < 8000) && (k0+c4 < 2000);
        pa[i] = ok ? *(const float4*)(Ab + (size_t)row*2000 + k0+c4) : make_float4(0.f,0.f,0.f,0.f);
      }
    }
  };
  auto storeA = [&](int kt){
    const int buf = kt&1;
    #pragma unroll
    for (int i=0;i<2;i++){
      int idx = i*512+tid, row = idx>>3, c4 = (idx&7)*4;
      ushort4 o; o.x=f2bf(pa[i].x); o.y=f2bf(pa[i].y); o.z=f2bf(pa[i].z); o.w=f2bf(pa[i].w);
      *(ushort4*)(&As[buf*4096 + idx*4]) = o;
      At[buf*4352 + (c4+0)*136 + (row ^ ((((c4+0)>>3)&3)<<3))] = o.x;
      At[buf*4352 + (c4+1)*136 + (row ^ ((((c4+1)>>3)&3)<<3))] = o.y;
      At[buf*4352 + (c4+2)*136 + (row ^ ((((c4+2)>>3)&3)<<3))] = o.z;
      At[buf*4352 + (c4+3)*136 + (row ^ ((((c4+3)>>3)&3)<<3))] = o.w;
    }
  };
  auto stageB = [&](int kt){
    const int buf = kt&1, k0 = kt*32;
    #pragma unroll
    for (int i=0;i<2;i++){
      int idx = i*512+tid;
      int row = idx>>2, c8 = (idx&3)*8;
      GLL16(Bb + (size_t)row*2048 + k0+c8, &Bs[buf*8192 + (i*512 + w*64)*8]);
    }
  };

  f32x4 acc[4][4];
  #pragma unroll
  for (int i=0;i<4;i++)
    #pragma unroll
    for (int j=0;j<4;j++) acc[i][j] = (f32x4){0.f,0.f,0.f,0.f};

  loadA(0, edge_blk); stageB(0);
  for (int kt=0; kt<64; kt++){
    storeA(kt);
    __syncthreads();
    if (kt+1 < 64){ loadA(kt+1, edge_blk || (kt+1 >= 62)); stageB(kt+1); }
    const int buf = kt&1, k0 = kt*32;
    // HT write: 32(k) x 128(m) tile, coalesced 16B stores
    {
      int kk = tid>>4, c = tid&15, m0 = c*8;
      if (bm + m0 < 8000){
        u16x8 v = *(const u16x8*)(&At[buf*4352 + kk*136 + (m0 ^ (((kk>>3)&3)<<3))]);
        *(u16x8*)(HTb + (size_t)(k0+kk)*8000 + bm + m0) = v;
      }
    }
    bf16x8 af[4], bf[4];
    #pragma unroll
    for (int mi=0;mi<4;mi++) af[mi] = *(const bf16x8*)(&As[buf*4096 + (wm+mi*16+l16)*32 + quad*8]);
    #pragma unroll
    for (int ni=0;ni<4;ni++) bf[ni] = *(const bf16x8*)(&Bs[buf*8192 + (wn+ni*16+l16)*32 + quad*8]);
    #pragma unroll
    for (int mi=0;mi<4;mi++)
      #pragma unroll
      for (int ni=0;ni<4;ni++)
        acc[mi][ni] = __builtin_amdgcn_mfma_f32_16x16x32_bf16(af[mi], bf[ni], acc[mi][ni], 0,0,0);
  }

  // ---- phase transition: all waves done with As/At/Bs reads
  __syncthreads();
  // stage W1(t=0,kt=0) into Bs[0] (overlaps Es write)
  {
    int row = tid>>2, c8 = (tid&3)*8;
    GLL16(W1T + (size_t)row*256 + c8, &Bs[0*8192 + (w*64)*8]);
  }
  // edges tile -> Es[kt=d>>5][m][d&31]  (zeros for OOB rows via guarded loads)
  #pragma unroll
  for (int mi=0;mi<4;mi++){
    #pragma unroll
    for (int r=0;r<4;r++){
      int m = wm + mi*16 + quad*4 + r;
      #pragma unroll
      for (int ni=0;ni<4;ni++){
        int d = wn + ni*16 + l16;
        Es[(d>>5)*4096 + m*32 + (d&31)] = f2bf(acc[mi][ni][r]);
      }
    }
  }
  __syncthreads();

  // ---- phase 2: per-type MLP on the LDS-resident tile
  const int wm1 = (w&1)*64, wh1 = ((w>>1)&3)*32;   // GEMM1: 128m x 128h
  const int wd2 = (w&3)*64, wm2 = (w>>2)*64;       // GEMM2: 256d x 128m

  auto stageW1 = [&](int t, int kt){   // W1T[t] tile [128 h][32 k], 8KB
    const int buf = kt&1;
    int row = tid>>2, c8 = (tid&3)*8;
    GLL16(W1T + ((size_t)t*128 + row)*256 + kt*32 + c8, &Bs[buf*8192 + (w*64)*8]);
  };
  auto stageW2 = [&](int t, int kk){   // W2T[t] tile [256 d][32 k], 16KB
    const int buf = kk&1;
    #pragma unroll
    for (int i=0;i<2;i++){
      int idx = i*512+tid, row = idx>>2, c8 = (idx&3)*8;
      GLL16(W2T + ((size_t)t*256 + row)*128 + kk*32 + c8, &Bs[buf*8192 + (i*512 + w*64)*8]);
    }
  };

  f32x4 acc2[4][4];
  #pragma unroll
  for (int i=0;i<4;i++)
    #pragma unroll
    for (int j=0;j<4;j++) acc2[i][j] = (f32x4){0.f,0.f,0.f,0.f};

  for (int t=0;t<5;t++){
    f32x4 acc1[4][2];
    #pragma unroll
    for (int i=0;i<4;i++){ acc1[i][0] = (f32x4){0.f,0.f,0.f,0.f}; acc1[i][1] = (f32x4){0.f,0.f,0.f,0.f}; }
    // GEMM1: hidden = edges @ W1T[t]
    for (int kt=0;kt<8;kt++){
      if (kt<7) stageW1(t,kt+1); else stageW2(t,0);
      const int buf = kt&1;
      bf16x8 af[4], bfr[2];
      #pragma unroll
      for (int mi=0;mi<4;mi++) af[mi] = *(const bf16x8*)(&Es[kt*4096 + (wm1+mi*16+l16)*32 + quad*8]);
      #pragma unroll
      for (int ni=0;ni<2;ni++) bfr[ni] = *(const bf16x8*)(&Bs[buf*8192 + (wh1+ni*16+l16)*32 + quad*8]);
      #pragma unroll
      for (int mi=0;mi<4;mi++)
        #pragma unroll
        for (int ni=0;ni<2;ni++)
          acc1[mi][ni] = __builtin_amdgcn_mfma_f32_16x16x32_bf16(af[mi], bfr[ni], acc1[mi][ni], 0,0,0);
      __syncthreads();
    }
    // epilogue1: relu + bias + ed-scale -> Hs[ch>>5][m][ch&31]
    #pragma unroll
    for (int mi=0;mi<4;mi++){
      #pragma unroll
      for (int r=0;r<4;r++){
        int lrow = wm1 + mi*16 + quad*4 + r;
        float s = eds[lrow*5 + t];
        #pragma unroll
        for (int ni=0;ni<2;ni++){
          int ch = wh1 + ni*16 + l16;
          float v = fmaxf(acc1[mi][ni][r] + b1s[t*128 + ch], 0.f) * s;
          Hs[(ch>>5)*4096 + lrow*32 + (ch&31)] = f2bf(v);
        }
      }
    }
    __syncthreads();
    // GEMM2 (transposed): acc2[d][m] += W2T[t] x hidden
    for (int kk=0;kk<4;kk++){
      if (kk<3) stageW2(t,kk+1); else if (t<4) stageW1(t+1,0);
      const int buf = kk&1;
      bf16x8 af2[4], bf2[4];
      #pragma unroll
      for (int mi=0;mi<4;mi++) af2[mi] = *(const bf16x8*)(&Bs[buf*8192 + (wd2+mi*16+l16)*32 + quad*8]);
      #pragma unroll
      for (int ni=0;ni<4;ni++) bf2[ni] = *(const bf16x8*)(&Hs[kk*4096 + (wm2+ni*16+l16)*32 + quad*8]);
      #pragma unroll
      for (int mi=0;mi<4;mi++)
        #pragma unroll
        for (int ni=0;ni<4;ni++)
          acc2[mi][ni] = __builtin_amdgcn_mfma_f32_16x16x32_bf16(af2[mi], bf2[ni], acc2[mi][ni], 0,0,0);
      __syncthreads();
    }
  }
  // epilogue2: add bias-dot, write EFt[b][d][e] directly
  #pragma unroll
  for (int mi=0;mi<4;mi++){
    #pragma unroll
    for (int r=0;r<4;r++){
      int d = wd2 + mi*16 + quad*4 + r;
      #pragma unroll
      for (int ni=0;ni<4;ni++){
        int mc = wm2 + ni*16 + l16;
        int e = bm + mc;
        if (e < 8000){
          float bias = eds[mc*5+0]*b2s[d] + eds[mc*5+1]*b2s[256+d] + eds[mc*5+2]*b2s[512+d]
                     + eds[mc*5+3]*b2s[768+d] + eds[mc*5+4]*b2s[1024+d];
          EFt[((size_t)b*256 + d)*8000 + e] = f2bf(acc2[mi][ni][r] + bias);
        }
      }
    }
  }
}

// ---------------- G3: part[ks][b,m,d] = sum_{e in slice} HT[b,m,e]*EFt[b,d,e]
// 1-D grid of 256, XCD-chunked swizzle: each XCD sees one b (EFt[b]=4MB fits its L2).
__global__ __launch_bounds__(512,2) void g3_kernel(
    const u16* __restrict__ HT, const u16* __restrict__ EFt, float* __restrict__ part){
  __shared__ u16 As[2][128*32];
  __shared__ u16 Bs[2][256*32];
  const int wg = ((int)blockIdx.x & 7)*32 + ((int)blockIdx.x >> 3);   // bijective, 256%8==0
  const int bm = (wg & 15)*128, ks = (wg>>4)&3, b = wg>>6;
  const int tid = threadIdx.x;
  const int w = tid>>6, quad = (tid&63)>>4, l16 = tid&15;
  const int wm = (w&1)*64, wn = (w>>1)*64;
  const u16* Ab = HT + (size_t)b*2048*8000 + (size_t)bm*8000;
  const u16* Bb = EFt + (size_t)b*256*8000;
  const int it0 = (250*ks)/4, it1 = (250*(ks+1))/4;

  auto stage = [&](int kt){
    const int buf = kt&1, k0 = kt*32;
    {
      int row = tid>>2, c8 = (tid&3)*8;
      GLL16(Ab + (size_t)row*8000 + k0+c8, &As[buf][(w*64)*8]);
    }
    #pragma unroll
    for (int i=0;i<2;i++){
      int idx = i*512+tid, row = idx>>2, c8 = (idx&3)*8;
      GLL16(Bb + (size_t)row*8000 + k0+c8, &Bs[buf][(i*512 + w*64)*8]);
    }
  };

  f32x4 acc[4][4];
  #pragma unroll
  for (int i=0;i<4;i++)
    #pragma unroll
    for (int j=0;j<4;j++) acc[i][j] = (f32x4){0.f,0.f,0.f,0.f};

  stage(it0);
  for (int kt=it0; kt<it1; kt++){
    __syncthreads();
    if (kt+1 < it1) stage(kt+1);
    const int buf = kt&1;
    bf16x8 af[4], bf[4];
    #pragma unroll
    for (int mi=0;mi<4;mi++) af[mi] = *(const bf16x8*)(&As[buf][(wm+mi*16+l16)*32 + quad*8]);
    #pragma unroll
    for (int ni=0;ni<4;ni++) bf[ni] = *(const bf16x8*)(&Bs[buf][(wn+ni*16+l16)*32 + quad*8]);
    #pragma unroll
    for (int mi=0;mi<4;mi++)
      #pragma unroll
      for (int ni=0;ni<4;ni++)
        acc[mi][ni] = __builtin_amdgcn_mfma_f32_16x16x32_bf16(af[mi], bf[ni], acc[mi][ni], 0,0,0);
  }
  float* dst0 = part + ((size_t)(b*4 + ks)*2048)*256;
  #pragma unroll
  for (int mi=0;mi<4;mi++){
    #pragma unroll
    for (int r=0;r<4;r++){
      int gm = bm + wm + mi*16 + quad*4 + r;
      float* dst = dst0 + (size_t)gm*256;
      #pragma unroll
      for (int ni=0;ni<4;ni++) dst[wn + ni*16 + l16] = acc[mi][ni][r];
    }
  }
}

// ---------------- assemble: out[b,n,:256] = sum_ks part ; out[b,n,256:] = ori[b,n,:]
__global__ void assemble_kernel(const float* __restrict__ part, const float* __restrict__ ori,
                                float* __restrict__ out){
  const int b = blockIdx.y;
  int u = blockIdx.x*256 + threadIdx.x;          // 500*256 = 128000 = 2000*64
  int n = u>>6, c4 = (u&63)*4;
  f32x4 s = (f32x4){0.f,0.f,0.f,0.f};
  #pragma unroll
  for (int ks=0; ks<4; ks++)
    s += *(const f32x4*)(part + ((size_t)(b*4+ks)*2048 + n)*256 + c4);
  float* dst = out + ((size_t)(b*2000+n))*512;
  *(f32x4*)(dst + c4) = s;
  *(f32x4*)(dst + 256 + c4) = *(const f32x4*)(ori + ((size_t)(b*2000+n))*256 + c4);
}

extern "C" void kernel_launch(void* const* d_in, const int* in_sizes, int n_in,
                              void* d_out, int out_size, void* d_ws, size_t ws_size,
                              hipStream_t stream) {
  const float* ed  = (const float*)d_in[0];   // [4,8000,5]
  const float* Hm  = (const float*)d_in[1];   // [4,8000,2000]
  const float* ori = (const float*)d_in[2];   // [4,2000,256]
  const float* W1  = (const float*)d_in[3];   // [5,256,128]
  const float* b1  = (const float*)d_in[4];   // [5,128]
  const float* W2  = (const float*)d_in[5];   // [5,128,256]
  const float* b2  = (const float*)d_in[6];   // [5,256]
  float* out = (float*)d_out;                 // [4,2000,512]
  char* ws = (char*)d_ws;

  u16* HT    = (u16*)(ws);                 // 4*2048*8000*2 = 131,072,000
  u16* oriT  = (u16*)(ws + 131072000);     // 4*256*2048*2  =   4,194,304
  u16* W1T   = (u16*)(ws + 135266304);     // 5*128*256*2   =     327,680
  u16* W2T   = (u16*)(ws + 135593984);     // 5*256*128*2   =     327,680
  u16* EFt   = (u16*)(ws + 152305664);     // 4*256*8000*2  =  16,384,000
  float* part = (float*)(ws + 168689664);  // 4*4*2048*256*4 = 33,554,432 (end ~202.2 MB)

  hipLaunchKernelGGL(transpose_f32, dim3(64,8,4), dim3(256), 0, stream,
                     ori, oriT, 2000, 256, 2048, 512000L, 524288L);
  hipLaunchKernelGGL(transpose_f32, dim3(8,4,5), dim3(256), 0, stream,
                     W1, W1T, 256, 128, 256, 32768L, 32768L);
  hipLaunchKernelGGL(transpose_f32, dim3(4,8,5), dim3(256), 0, stream,
                     W2, W2T, 128, 256, 128, 32768L, 32768L);

  hipLaunchKernelGGL(g1mlp_kernel, dim3(63,4), dim3(512), 0, stream,
                     Hm, oriT, W1T, W2T, b1, b2, ed, HT, EFt);
  hipLaunchKernelGGL(g3_kernel, dim3(256), dim3(512), 0, stream, HT, EFt, part);
  hipLaunchKernelGGL(assemble_kernel, dim3(500,4), dim3(256), 0, stream, part, ori, out);

  (void)in_sizes; (void)n_in; (void)ws_size;
}